// Round 13
// baseline (169.658 us; speedup 1.0000x reference)
//
#include <hip/hip_runtime.h>

// SFM recurrent model via MFMA: B=2048, T=60, D=6, H=64, F=10, O=1.
//
// R1-R3: VALU readlane-GEMV, 183 us. R4: MFMA split-bf16 -> 100 us.
// R5-R11: 78-111 us band. R12: transposed GEMM (m=hcol, A=U^T static;
//   n-cols = h_hi|h_lo) -> 73 us best; but NB=8 = 1 blk/CU -> 51% idle
//   (both waves drain at same barrier). Session-wide: idle 28% with 2
//   barrier domains (R9) vs 45-51% with 1 (R8/R12). Slide is the only
//   idle-cutter that ever worked.
// R13: R12 orientation x R9 occupancy. NB=4, 256 thr, 512 blocks ->
//   2 blk/CU. Cols 0-3 h_hi(b), 4-7 h_lo (8-15 zero). k=64 exact:
//   4 chained MFMAs/tile; x@W+bias in P (fp32 fma), fre x-part = xf
//   precompute (R9). Wave w = gate w (4 tiles); wave 0 += fre tile.
//   68 MFMA/block, 136/CU/step = 544 cyc/SIMD vs R12 383, R9 816.
//
// Layouts (verified R12): A[m=lane&15][k=q*8+j]; B[k=q*8+j][n=lane&15];
// C col=lane&15 (n: batch/part), row=q*4+reg (m: hcol in tile).

#define BB 2048
#define TT 60
#define DD 6
#define HH 64
#define FF 10
#define NB 4      // batches per block

#define XCS 964   // xc per-batch stride in floats (60*16 + 4 pad)
#define HSK 72    // hsp2 row stride in shorts (16 rows: 0-3 hi, 4-7 lo, 8-15 zero)
#define ZC 68     // zt hcol stride in floats

typedef short bf16x8 __attribute__((ext_vector_type(8)));
typedef float f32x4  __attribute__((ext_vector_type(4)));

__device__ __forceinline__ unsigned short f2bf(float f) {
    union { float f; unsigned u; } v; v.f = f;
    unsigned r = v.u + 0x7fffu + ((v.u >> 16) & 1u);   // RNE
    return (unsigned short)(r >> 16);
}
__device__ __forceinline__ float bf2f(unsigned short b) {
    union { unsigned u; float f; } v; v.u = ((unsigned)b) << 16; return v.f;
}
__device__ __forceinline__ float hsig_f(float v) {
    return __builtin_amdgcn_fmed3f(fmaf(v, 0.16666666666666666f, 0.5f), 0.0f, 1.0f);
}
__device__ __forceinline__ float tanh_f(float x) {
    float xc = fminf(fmaxf(x, -12.0f), 12.0f);
    float e  = __builtin_amdgcn_exp2f(xc * 2.8853900817779268f); // 2*log2(e)
    return (e - 1.0f) * __builtin_amdgcn_rcpf(e + 1.0f);
}
__device__ __forceinline__ float uni(float v) {
    return __int_as_float(__builtin_amdgcn_readfirstlane(__float_as_int(v)));
}
__device__ __forceinline__ void pinv(bf16x8& v) { asm volatile("" : "+v"(v)); }

__global__ __launch_bounds__(256, 2)
void sfm_kernel(
    const float* __restrict__ x,
    const float* __restrict__ W_i,  const float* __restrict__ U_i,  const float* __restrict__ b_i,
    const float* __restrict__ W_ste,const float* __restrict__ U_ste,const float* __restrict__ b_ste,
    const float* __restrict__ W_fre,const float* __restrict__ U_fre,const float* __restrict__ b_fre,
    const float* __restrict__ W_c,  const float* __restrict__ U_c,  const float* __restrict__ b_c,
    const float* __restrict__ W_o,  const float* __restrict__ U_o,  const float* __restrict__ b_o,
    const float* __restrict__ U_a,  const float* __restrict__ b_a,
    const float* __restrict__ W_p,  const float* __restrict__ b_p,
    float* __restrict__ out)
{
    const int tid  = threadIdx.x;
    const int lane = tid & 63;
    const int wave = tid >> 6;      // 0..3 == gate id
    const int q    = lane >> 4;     // quad 0..3
    const int n16  = lane & 15;
    const int b0   = blockIdx.x * NB;

    __shared__ __align__(16) float xc[NB * XCS];            // [b][s][0..5]=x, [6..15]=xf
    __shared__ __align__(16) unsigned short hsp2[16 * HSK]; // rows 0-3 hi(b), 4-7 lo(b), 8-15 zero
    __shared__ __align__(16) float zt[4 * 8 * ZC];          // [g*8+col(part,b)][hcol]
    __shared__ __align__(16) float fb[NB * 12];             // zfre[b][f], parts+xf folded
    __shared__ __align__(16) float ctab[10 * 10 * 2];
    __shared__ float cstabB[10 * 2];
    __shared__ float red[4][NB];

    // ---- init 1: stage x fp32 (coalesced), base trig, zero h rows ----
    for (int i = tid; i < NB * TT * DD; i += 256) {
        const int b = i / (TT * DD), rem = i - b * (TT * DD);
        const int s = rem / DD, d = rem - s * DD;
        xc[b * XCS + s * 16 + d] = x[(size_t)b0 * (TT * DD) + i];
    }
    if (tid < 10) {
        const float CTc[10] = { 1.0f,  0.8090169943749475f,  0.30901699437494745f,
                               -0.30901699437494745f, -0.8090169943749475f, -1.0f,
                               -0.8090169943749475f, -0.30901699437494745f,
                                0.30901699437494745f,  0.8090169943749475f };
        const float STc[10] = { 0.0f,  0.5877852522924731f,  0.9510565162951535f,
                                0.9510565162951535f,  0.5877852522924731f,  0.0f,
                               -0.5877852522924731f, -0.9510565162951535f,
                               -0.9510565162951535f, -0.5877852522924731f };
        float cc = 0.0f, ss = 0.0f;
        #pragma unroll
        for (int j = 0; j < 10; ++j) if (tid == j) { cc = CTc[j]; ss = STc[j]; }
        cstabB[tid * 2] = cc; cstabB[tid * 2 + 1] = ss;
    }
    for (int i = tid; i < 16 * HSK; i += 256) hsp2[i] = 0;   // rows 8..15 stay zero
    __syncthreads();

    // ---- init 2: xf[b][s][f] = b_fre + x@W_fre; full ctab ----
    if (tid < NB * TT) {
        const int b = tid / TT, s = tid - b * TT;
        float xr[DD];
        #pragma unroll
        for (int d = 0; d < DD; ++d) xr[d] = xc[b * XCS + s * 16 + d];
        #pragma unroll
        for (int f = 0; f < FF; ++f) {
            float v = b_fre[f];
            #pragma unroll
            for (int d = 0; d < DD; ++d) v = fmaf(xr[d], W_fre[d * FF + f], v);
            xc[b * XCS + s * 16 + 6 + f] = v;
        }
    }
    if (tid < 100) {
        const int mm = tid / 10, ff = tid - mm * 10;
        const int idx = (ff * mm) % 10;
        ctab[tid * 2]     = cstabB[idx * 2];
        ctab[tid * 2 + 1] = cstabB[idx * 2 + 1];
    }

    // ---- A-frags (STATIC, U^T): wave w = gate w, tiles mt=0..3
    //      (hcol block mt*16); wave 0 tile 4 = fre. k = c*32+q*8+j (0..63). ----
    const int NTILE = (wave == 0) ? 5 : 4;
    const float* Ug = (wave == 0) ? U_i : (wave == 1) ? U_ste : (wave == 2) ? U_c : U_o;
    bf16x8 Ah[5][2], Al[5][2];
    #pragma unroll
    for (int t = 0; t < 5; ++t) {
        if (t >= NTILE) continue;
        const bool isfre = (t == 4);
        #pragma unroll
        for (int c = 0; c < 2; ++c) {
            #pragma unroll
            for (int j = 0; j < 8; ++j) {
                const int kv = c * 32 + q * 8 + j;
                float v = 0.0f;
                if (!isfre)          v = Ug[kv * HH + t * 16 + n16];
                else if (n16 < FF)   v = U_fre[kv * FF + n16];
                const unsigned short hb = f2bf(v);
                Ah[t][c][j] = (short)hb;
                Al[t][c][j] = (short)f2bf(v - bf2f(hb));
            }
            pinv(Ah[t][c]); pinv(Al[t][c]);
        }
    }

    // ---- pointwise consts: pb = tid&3, pc = tid>>2 ----
    const int pb = tid & (NB - 1);
    const int pc = tid >> 2;
    const float bav = b_a[pc];
    const float wpv = W_p[pc];
    const float bpv = uni(b_p[0]);
    float uav[FF];
    #pragma unroll
    for (int f = 0; f < FF; ++f) uav[f] = uni(U_a[f]);
    float wxi[DD], wxs[DD], wxc[DD], wxo[DD];
    #pragma unroll
    for (int d = 0; d < DD; ++d) {
        wxi[d] = W_i[d * HH + pc];  wxs[d] = W_ste[d * HH + pc];
        wxc[d] = W_c[d * HH + pc];  wxo[d] = W_o[d * HH + pc];
    }
    const float bi = b_i[pc], bs = b_ste[pc], bc = b_c[pc], bo = b_o[pc];

    float Sre[FF], Sim[FF];
    #pragma unroll
    for (int f = 0; f < FF; ++f) { Sre[f] = 0.0f; Sim[f] = 0.0f; }
    float hv = 0.0f;

    const unsigned short* hrp = &hsp2[n16 * HSK];   // row n16: b-hi/lo/zero

    __syncthreads();

    int m = 1;  // (s+1) % 10
    for (int s = 0; s < TT; ++s) {
        // ---- B-frags: 2 x ds_read_b128 (rows pre-structured) ----
        const bf16x8 B0 = *(const bf16x8*)&hrp[q * 8];
        const bf16x8 B1 = *(const bf16x8*)&hrp[32 + q * 8];

        // ---- MFMAs: per tile 4 chained (Ah,B0)(Al,B0)(Ah,B1)(Al,B1) ----
        f32x4 acc[5];
        #pragma unroll
        for (int t = 0; t < 5; ++t) {
            if (t >= NTILE) continue;
            f32x4 a = {0.0f, 0.0f, 0.0f, 0.0f};
            a = __builtin_amdgcn_mfma_f32_16x16x32_bf16(Ah[t][0], B0, a, 0, 0, 0);
            a = __builtin_amdgcn_mfma_f32_16x16x32_bf16(Al[t][0], B0, a, 0, 0, 0);
            a = __builtin_amdgcn_mfma_f32_16x16x32_bf16(Ah[t][1], B1, a, 0, 0, 0);
            a = __builtin_amdgcn_mfma_f32_16x16x32_bf16(Al[t][1], B1, a, 0, 0, 0);
            acc[t] = a;
        }

        // ---- write z: lane col n16<8 (0-3 hi-part, 4-7 lo-part) ----
        if (n16 < 8) {
            #pragma unroll
            for (int t = 0; t < 4; ++t)
                *(f32x4*)&zt[(wave * 8 + n16) * ZC + t * 16 + q * 4] = acc[t];
        }
        if (wave == 0) {   // fre: fold lo cols via shfl_xor(4), add xf, write
            f32x4 af;
            #pragma unroll
            for (int r = 0; r < 4; ++r)
                af[r] = acc[4][r] + __shfl_xor(acc[4][r], 4, 64);
            if (n16 < 4) {
                #pragma unroll
                for (int r = 0; r < 4; ++r) {
                    const int f = q * 4 + r;
                    if (f < FF) fb[n16 * 12 + f] = af[r] + xc[n16 * XCS + s * 16 + 6 + f];
                }
            }
        }
        __syncthreads();

        // ---- P: batch pb, col pc; z = hi-part + lo-part + x@W + bias ----
        const float4 xv4 = *(const float4*)&xc[pb * XCS + s * 16];
        const float2 xv2 = *(const float2*)&xc[pb * XCS + s * 16 + 4];
        const float xa[DD] = {xv4.x, xv4.y, xv4.z, xv4.w, xv2.x, xv2.y};

        float vi = bi, vs = bs, vc = bc, vo = bo;
        #pragma unroll
        for (int d = 0; d < DD; ++d) {
            vi = fmaf(xa[d], wxi[d], vi);
            vs = fmaf(xa[d], wxs[d], vs);
            vc = fmaf(xa[d], wxc[d], vc);
            vo = fmaf(xa[d], wxo[d], vo);
        }
        const float zi = zt[(0 * 8 + pb) * ZC + pc] + zt[(0 * 8 + pb + 4) * ZC + pc] + vi;
        const float zs = zt[(1 * 8 + pb) * ZC + pc] + zt[(1 * 8 + pb + 4) * ZC + pc] + vs;
        const float zc = zt[(2 * 8 + pb) * ZC + pc] + zt[(2 * 8 + pb + 4) * ZC + pc] + vc;
        const float zo = zt[(3 * 8 + pb) * ZC + pc] + zt[(3 * 8 + pb + 4) * ZC + pc] + vo;

        float fr[FF];
        #pragma unroll
        for (int f = 0; f < FF; ++f) fr[f] = hsig_f(fb[pb * 12 + f]);

        const float iv  = hsig_f(zi);
        const float stv = hsig_f(zs);
        const float ov  = hsig_f(zo);
        const float cv  = iv * tanh_f(zc);

        const float* tp = &ctab[m * 20];
        float aacc0 = bav, aacc1 = 0.0f;
        #pragma unroll
        for (int f = 0; f < FF; ++f) {
            const float2 tv = *(const float2*)&tp[f * 2];
            const float fc = stv * fr[f];
            Sre[f] = fmaf(fc, Sre[f], cv * tv.x);
            Sim[f] = fmaf(fc, Sim[f], cv * tv.y);
            const float A = fmaf(Sim[f], Sim[f], Sre[f] * Sre[f]);
            if (f & 1) aacc1 = fmaf(A, uav[f], aacc1);
            else       aacc0 = fmaf(A, uav[f], aacc0);
        }
        hv = ov * tanh_f(aacc0 + aacc1);

        // split h -> bf16 hi/lo rows (the ONLY conversion point)
        {
            const unsigned short hb = f2bf(hv);
            hsp2[pb * HSK + pc]       = hb;
            hsp2[(4 + pb) * HSK + pc] = f2bf(hv - bf2f(hb));
        }
        if (++m == 10) m = 0;
        __syncthreads();
    }

    // ---- output: out[b] = sum_col h*W_p + b_p ----
    float val = hv * wpv;
    val += __shfl_xor(val, 4, 64);
    val += __shfl_xor(val, 8, 64);
    val += __shfl_xor(val, 16, 64);
    val += __shfl_xor(val, 32, 64);
    if (lane < NB) red[wave][lane] = val;
    __syncthreads();
    if (tid < NB)
        out[b0 + tid] = red[0][tid] + red[1][tid] + red[2][tid] + red[3][tid] + bpv;
}

extern "C" void kernel_launch(void* const* d_in, const int* in_sizes, int n_in,
                              void* d_out, int out_size, void* d_ws, size_t ws_size,
                              hipStream_t stream) {
    (void)in_sizes; (void)n_in; (void)d_ws; (void)ws_size; (void)out_size;
    const float* x     = (const float*)d_in[0];
    const float* W_i   = (const float*)d_in[1];
    const float* U_i   = (const float*)d_in[2];
    const float* b_i   = (const float*)d_in[3];
    const float* W_ste = (const float*)d_in[4];
    const float* U_ste = (const float*)d_in[5];
    const float* b_ste = (const float*)d_in[6];
    const float* W_fre = (const float*)d_in[7];
    const float* U_fre = (const float*)d_in[8];
    const float* b_fre = (const float*)d_in[9];
    const float* W_c   = (const float*)d_in[10];
    const float* U_c   = (const float*)d_in[11];
    const float* b_c   = (const float*)d_in[12];
    const float* W_o   = (const float*)d_in[13];
    const float* U_o   = (const float*)d_in[14];
    const float* b_o   = (const float*)d_in[15];
    const float* U_a   = (const float*)d_in[16];
    const float* b_a   = (const float*)d_in[17];
    const float* W_p   = (const float*)d_in[18];
    const float* b_p   = (const float*)d_in[19];

    sfm_kernel<<<BB / NB, 256, 0, stream>>>(
        x, W_i, U_i, b_i, W_ste, U_ste, b_ste, W_fre, U_fre, b_fre,
        W_c, U_c, b_c, W_o, U_o, b_o, U_a, b_a, W_p, b_p, (float*)d_out);
}

// Round 14
// 160.640 us; speedup vs baseline: 1.0561x; 1.0561x over previous
//
#include <hip/hip_runtime.h>

// SFM recurrent model via MFMA: B=2048, T=60, D=6, H=64, F=10, O=1.
//
// R1-R13 summary: best R12 = 73 us. Whole band 73-98 us across all
// {NB, waves, blk/CU} combos. Invariant cost: 2 barriers/step + z LDS
// round-trip between MFMA phase and pointwise phase (~1500 idle
// cyc/step). Busy work is small (R12: 383 MFMA + 1042 VALU cyc/step).
// R14: z NEVER leaves registers. Wave w owns ALL 4 gate tiles for hcol
// block [16w,16w+16) (transposed orientation: A=U^T, m=hcol, n-cols =
// h_hi(b0..7)|h_lo(b0..7)). After MFMA, lane (n16,q) holds
// z_g[hcol=16w+4q+r][b=n16&7,part]; shfl_xor(8) folds parts; same lane
// does pointwise for (b=n16&7, 2 hcols). ONE barrier/step (h only).
// fre duplicated per wave (+6 MFMA) and exchanged via per-wave LDS
// region (intra-wave ds write->read, no barrier needed).
// 256 blocks x 256 thr, NB=8, 1 wave/SIMD (512-VGPR budget).
//
// Layouts (verified R12): A[m=lane&15][k=q*8+j]; B[k=q*8+j][n=lane&15];
// C col=lane&15 (n: b,part), row=q*4+reg (m: hcol in tile).

#define BB 2048
#define TT 60
#define DD 6
#define HH 64
#define FF 10
#define NB 8      // batches per block

#define XS 968    // xsp per-batch stride in shorts (60*16 + 8 pad)
#define HSK 72    // hsp2 row stride in shorts (16 rows: 0-7 hi(b), 8-15 lo(b))

typedef short bf16x8 __attribute__((ext_vector_type(8)));
typedef float f32x4  __attribute__((ext_vector_type(4)));

__device__ __forceinline__ unsigned short f2bf(float f) {
    union { float f; unsigned u; } v; v.f = f;
    unsigned r = v.u + 0x7fffu + ((v.u >> 16) & 1u);   // RNE
    return (unsigned short)(r >> 16);
}
__device__ __forceinline__ float bf2f(unsigned short b) {
    union { unsigned u; float f; } v; v.u = ((unsigned)b) << 16; return v.f;
}
__device__ __forceinline__ float hsig_f(float v) {
    return __builtin_amdgcn_fmed3f(fmaf(v, 0.16666666666666666f, 0.5f), 0.0f, 1.0f);
}
__device__ __forceinline__ float tanh_f(float x) {
    float xc = fminf(fmaxf(x, -12.0f), 12.0f);
    float e  = __builtin_amdgcn_exp2f(xc * 2.8853900817779268f); // 2*log2(e)
    return (e - 1.0f) * __builtin_amdgcn_rcpf(e + 1.0f);
}
__device__ __forceinline__ float uni(float v) {
    return __int_as_float(__builtin_amdgcn_readfirstlane(__float_as_int(v)));
}
__device__ __forceinline__ void pinv(bf16x8& v) { asm volatile("" : "+v"(v)); }

__global__ __launch_bounds__(256)
__attribute__((amdgpu_waves_per_eu(1, 1)))
void sfm_kernel(
    const float* __restrict__ x,
    const float* __restrict__ W_i,  const float* __restrict__ U_i,  const float* __restrict__ b_i,
    const float* __restrict__ W_ste,const float* __restrict__ U_ste,const float* __restrict__ b_ste,
    const float* __restrict__ W_fre,const float* __restrict__ U_fre,const float* __restrict__ b_fre,
    const float* __restrict__ W_c,  const float* __restrict__ U_c,  const float* __restrict__ b_c,
    const float* __restrict__ W_o,  const float* __restrict__ U_o,  const float* __restrict__ b_o,
    const float* __restrict__ U_a,  const float* __restrict__ b_a,
    const float* __restrict__ W_p,  const float* __restrict__ b_p,
    float* __restrict__ out)
{
    const int tid  = threadIdx.x;
    const int lane = tid & 63;
    const int wave = tid >> 6;      // 0..3 == hcol block
    const int q    = lane >> 4;     // quad 0..3
    const int n16  = lane & 15;
    const int b0   = blockIdx.x * NB;

    __shared__ __align__(16) unsigned short xsp[NB * XS];   // presplit x records
    __shared__ __align__(16) unsigned short hsp2[16 * HSK]; // rows 0-7 hhi(b), 8-15 hlo(b)
    __shared__ __align__(16) float fbw[4][8][16];           // per-wave fre exchange [w][b][f]
    __shared__ __align__(16) float ctab[10 * 10 * 2];
    __shared__ float cstabB[10 * 2];
    __shared__ float red[4][NB];

    // ---- init 1: stage + pre-split x (480 records over 256 thr) ----
    for (int item = tid; item < NB * TT; item += 256) {
        const float* xg = x + (size_t)b0 * (TT * DD) + item * DD;
        const int b = item / TT, s = item - b * TT;
        unsigned short* dst = &xsp[b * XS + s * 16];
        #pragma unroll
        for (int d = 0; d < DD; ++d) {
            const float v = xg[d];
            const unsigned short hb = f2bf(v);
            dst[d]     = hb;
            dst[8 + d] = f2bf(v - bf2f(hb));
        }
        dst[6] = 0x3F80; dst[7] = 0;   // k=70 bias row: 1.0 (hi), k=71: 0
        dst[14] = 0; dst[15] = 0;      // lo-part bias rows: 0
    }
    if (tid < 10) {
        const float CTc[10] = { 1.0f,  0.8090169943749475f,  0.30901699437494745f,
                               -0.30901699437494745f, -0.8090169943749475f, -1.0f,
                               -0.8090169943749475f, -0.30901699437494745f,
                                0.30901699437494745f,  0.8090169943749475f };
        const float STc[10] = { 0.0f,  0.5877852522924731f,  0.9510565162951535f,
                                0.9510565162951535f,  0.5877852522924731f,  0.0f,
                               -0.5877852522924731f, -0.9510565162951535f,
                               -0.9510565162951535f, -0.5877852522924731f };
        float cc = 0.0f, ss = 0.0f;
        #pragma unroll
        for (int j = 0; j < 10; ++j) if (tid == j) { cc = CTc[j]; ss = STc[j]; }
        cstabB[tid * 2] = cc; cstabB[tid * 2 + 1] = ss;
    }
    for (int i = tid; i < 16 * HSK; i += 256) hsp2[i] = 0;
    __syncthreads();
    if (tid < 100) {
        const int mm = tid / 10, ff = tid - mm * 10;
        const int idx = (ff * mm) % 10;
        ctab[tid * 2]     = cstabB[idx * 2];
        ctab[tid * 2 + 1] = cstabB[idx * 2 + 1];
    }

    // ---- A-frags (STATIC): tiles t=0..3 = gate t (cols wave*16+n16),
    //      t=4 = fre (cols n16<10). k = c*32+q*8+j: 0-63 U, 64-69 W, 70 b. ----
    bf16x8 Ah[5][3], Al[5][3];
    #pragma unroll
    for (int t = 0; t < 5; ++t) {
        const float* Up = (t==0)?U_i:(t==1)?U_ste:(t==2)?U_c:(t==3)?U_o:U_fre;
        const float* Wp = (t==0)?W_i:(t==1)?W_ste:(t==2)?W_c:(t==3)?W_o:W_fre;
        const float* bp = (t==0)?b_i:(t==1)?b_ste:(t==2)?b_c:(t==3)?b_o:b_fre;
        const int nd  = (t < 4) ? HH : FF;
        const int col = (t < 4) ? (wave * 16 + n16) : n16;
        const bool ok = (t < 4) || (n16 < FF);
        #pragma unroll
        for (int c = 0; c < 3; ++c) {
            #pragma unroll
            for (int j = 0; j < 8; ++j) {
                const int kv = c * 32 + q * 8 + j;
                float v = 0.0f;
                if (ok) {
                    if      (kv < 64)  v = Up[kv * nd + col];
                    else if (kv < 70)  v = Wp[(kv - 64) * nd + col];
                    else if (kv == 70) v = bp[col];
                }
                const unsigned short hb = f2bf(v);
                Ah[t][c][j] = (short)hb;
                Al[t][c][j] = (short)f2bf(v - bf2f(hb));
            }
            pinv(Ah[t][c]); pinv(Al[t][c]);
        }
    }

    // ---- per-lane pointwise identity: batch b, 2 hcols hc0, hc0+1 ----
    const int b   = n16 & 7;
    const int hi3 = n16 >> 3;
    const int hc0 = wave * 16 + q * 4 + hi3 * 2;
    const float ba0 = b_a[hc0], ba1 = b_a[hc0 + 1];
    const float wp0 = W_p[hc0], wp1 = W_p[hc0 + 1];
    const float bpv = uni(b_p[0]);
    float uav[FF];
    #pragma unroll
    for (int f = 0; f < FF; ++f) uav[f] = uni(U_a[f]);

    float Sre0[FF], Sim0[FF], Sre1[FF], Sim1[FF];
    #pragma unroll
    for (int f = 0; f < FF; ++f) { Sre0[f]=0.f; Sim0[f]=0.f; Sre1[f]=0.f; Sim1[f]=0.f; }
    float hv0 = 0.0f, hv1 = 0.0f;

    const unsigned short* hrp = &hsp2[n16 * HSK];
    const unsigned short* xrp = &xsp[b * XS + hi3 * 8];

    __syncthreads();

    int m = 1;  // (s+1) % 10
    for (int s = 0; s < TT; ++s) {
        // ---- B-frags: h rows (pre-structured) + x record (q0 -> k 64-71) ----
        const bf16x8 B0 = *(const bf16x8*)&hrp[q * 8];
        const bf16x8 B1 = *(const bf16x8*)&hrp[32 + q * 8];
        const bf16x8 xv = *(const bf16x8*)&xrp[s * 16];
        const bf16x8 zf8 = {0, 0, 0, 0, 0, 0, 0, 0};
        const bf16x8 B2 = (q == 0) ? xv : zf8;

        // ---- MFMAs: 5 tiles x 6 chained (Ah,B)(Al,B) x 3 chunks ----
        f32x4 acc[5];
        #pragma unroll
        for (int t = 0; t < 5; ++t) {
            f32x4 a = {0.0f, 0.0f, 0.0f, 0.0f};
            a = __builtin_amdgcn_mfma_f32_16x16x32_bf16(Ah[t][0], B0, a, 0, 0, 0);
            a = __builtin_amdgcn_mfma_f32_16x16x32_bf16(Al[t][0], B0, a, 0, 0, 0);
            a = __builtin_amdgcn_mfma_f32_16x16x32_bf16(Ah[t][1], B1, a, 0, 0, 0);
            a = __builtin_amdgcn_mfma_f32_16x16x32_bf16(Al[t][1], B1, a, 0, 0, 0);
            a = __builtin_amdgcn_mfma_f32_16x16x32_bf16(Ah[t][2], B2, a, 0, 0, 0);
            a = __builtin_amdgcn_mfma_f32_16x16x32_bf16(Al[t][2], B2, a, 0, 0, 0);
            acc[t] = a;
        }

        // ---- fold hi+lo parts in-register (no LDS) ----
        f32x4 z[5];
        #pragma unroll
        for (int t = 0; t < 5; ++t) {
            #pragma unroll
            for (int r = 0; r < 4; ++r)
                z[t][r] = acc[t][r] + __shfl_xor(acc[t][r], 8, 64);
        }

        // ---- fre exchange via PER-WAVE LDS region (intra-wave, no barrier) ----
        if (n16 < 8) *(f32x4*)&fbw[wave][n16][q * 4] = z[4];
        asm volatile("" ::: "memory");
        const f32x4  fA = *(const f32x4*)&fbw[wave][b][0];
        const f32x4  fB = *(const f32x4*)&fbw[wave][b][4];
        const float2 fC = *(const float2*)&fbw[wave][b][8];
        float fr[FF];
        #pragma unroll
        for (int f = 0; f < 4; ++f) fr[f] = hsig_f(fA[f]);
        #pragma unroll
        for (int f = 0; f < 4; ++f) fr[4 + f] = hsig_f(fB[f]);
        fr[8] = hsig_f(fC.x); fr[9] = hsig_f(fC.y);

        // ---- select this lane's 2 hcols (rows hi3*2, hi3*2+1) ----
        const float zi0 = hi3 ? z[0][2] : z[0][0], zi1 = hi3 ? z[0][3] : z[0][1];
        const float zs0 = hi3 ? z[1][2] : z[1][0], zs1 = hi3 ? z[1][3] : z[1][1];
        const float zc0 = hi3 ? z[2][2] : z[2][0], zc1 = hi3 ? z[2][3] : z[2][1];
        const float zo0 = hi3 ? z[3][2] : z[3][0], zo1 = hi3 ? z[3][3] : z[3][1];

        const float iv0 = hsig_f(zi0), st0 = hsig_f(zs0), ov0 = hsig_f(zo0);
        const float iv1 = hsig_f(zi1), st1 = hsig_f(zs1), ov1 = hsig_f(zo1);
        const float cv0 = iv0 * tanh_f(zc0);
        const float cv1 = iv1 * tanh_f(zc1);

        const float* tp = &ctab[m * 20];
        float a00 = ba0, a01 = 0.0f, a10 = ba1, a11 = 0.0f;
        #pragma unroll
        for (int f = 0; f < FF; ++f) {
            const float2 tv = *(const float2*)&tp[f * 2];
            const float fc0 = st0 * fr[f];
            const float fc1 = st1 * fr[f];
            Sre0[f] = fmaf(fc0, Sre0[f], cv0 * tv.x);
            Sim0[f] = fmaf(fc0, Sim0[f], cv0 * tv.y);
            Sre1[f] = fmaf(fc1, Sre1[f], cv1 * tv.x);
            Sim1[f] = fmaf(fc1, Sim1[f], cv1 * tv.y);
            const float A0 = fmaf(Sim0[f], Sim0[f], Sre0[f] * Sre0[f]);
            const float A1 = fmaf(Sim1[f], Sim1[f], Sre1[f] * Sre1[f]);
            if (f & 1) { a01 = fmaf(A0, uav[f], a01); a11 = fmaf(A1, uav[f], a11); }
            else       { a00 = fmaf(A0, uav[f], a00); a10 = fmaf(A1, uav[f], a10); }
        }
        hv0 = ov0 * tanh_f(a00 + a01);
        hv1 = ov1 * tanh_f(a10 + a11);

        // ---- h -> bf16 hi/lo rows (the ONLY cross-wave product) ----
        {
            const unsigned short hA = f2bf(hv0);
            const unsigned short hB = f2bf(hv1);
            hsp2[b * HSK + hc0]           = hA;
            hsp2[(8 + b) * HSK + hc0]     = f2bf(hv0 - bf2f(hA));
            hsp2[b * HSK + hc0 + 1]       = hB;
            hsp2[(8 + b) * HSK + hc0 + 1] = f2bf(hv1 - bf2f(hB));
        }
        if (++m == 10) m = 0;
        __syncthreads();   // ONE barrier per step
    }

    // ---- output: out[b] = sum_hcol h*W_p + b_p ----
    float val = fmaf(hv0, wp0, hv1 * wp1);
    val += __shfl_xor(val, 8, 64);    // fold hi3
    val += __shfl_xor(val, 16, 64);   // fold q
    val += __shfl_xor(val, 32, 64);
    if (lane < 8) red[wave][lane] = val;
    __syncthreads();
    if (tid < NB)
        out[b0 + tid] = red[0][tid] + red[1][tid] + red[2][tid] + red[3][tid] + bpv;
}

extern "C" void kernel_launch(void* const* d_in, const int* in_sizes, int n_in,
                              void* d_out, int out_size, void* d_ws, size_t ws_size,
                              hipStream_t stream) {
    (void)in_sizes; (void)n_in; (void)d_ws; (void)ws_size; (void)out_size;
    const float* x     = (const float*)d_in[0];
    const float* W_i   = (const float*)d_in[1];
    const float* U_i   = (const float*)d_in[2];
    const float* b_i   = (const float*)d_in[3];
    const float* W_ste = (const float*)d_in[4];
    const float* U_ste = (const float*)d_in[5];
    const float* b_ste = (const float*)d_in[6];
    const float* W_fre = (const float*)d_in[7];
    const float* U_fre = (const float*)d_in[8];
    const float* b_fre = (const float*)d_in[9];
    const float* W_c   = (const float*)d_in[10];
    const float* U_c   = (const float*)d_in[11];
    const float* b_c   = (const float*)d_in[12];
    const float* W_o   = (const float*)d_in[13];
    const float* U_o   = (const float*)d_in[14];
    const float* b_o   = (const float*)d_in[15];
    const float* U_a   = (const float*)d_in[16];
    const float* b_a   = (const float*)d_in[17];
    const float* W_p   = (const float*)d_in[18];
    const float* b_p   = (const float*)d_in[19];

    sfm_kernel<<<BB / NB, 256, 0, stream>>>(
        x, W_i, U_i, b_i, W_ste, U_ste, b_ste, W_fre, U_fre, b_fre,
        W_c, U_c, b_c, W_o, U_o, b_o, U_a, b_a, W_p, b_p, (float*)d_out);
}